// Round 11
// baseline (124.638 us; speedup 1.0000x reference)
//
#include <hip/hip_runtime.h>

#define NUM_HEADS 16
#define HEAD_DIM  128
#define SEQ       2048
#define KT_STRIDE 8192   // bf16 elems per k-tile group in KF/VF (16 chunks * 512)

typedef __attribute__((ext_vector_type(8))) unsigned short us8;
typedef __attribute__((ext_vector_type(8))) __bf16 bf16x8;
typedef __attribute__((ext_vector_type(4))) float f32x4;
typedef __attribute__((ext_vector_type(16))) float f32x16;
typedef __attribute__((ext_vector_type(4))) unsigned u32x4;
typedef __attribute__((ext_vector_type(2))) unsigned u32x2;

static __device__ inline unsigned short f2bf(float x) {   // RNE
    union { float f; unsigned u; } v; v.f = x;
    unsigned r = v.u + 0x7FFFu + ((v.u >> 16) & 1u);
    return (unsigned short)(r >> 16);
}
static __device__ inline unsigned pk2bf(float a, float b) {
    return (unsigned)f2bf(a) | ((unsigned)f2bf(b) << 16);
}
static __device__ inline float fast_exp2(float x) {
#if __has_builtin(__builtin_amdgcn_exp2f)
    return __builtin_amdgcn_exp2f(x);
#else
    return exp2f(x);
#endif
}
// pack hi16(clo) into lo half, hi16(chi) into hi half (both truncated bf16)
static __device__ inline unsigned pack_hi(unsigned clo, unsigned chi) {
#if __has_builtin(__builtin_amdgcn_perm)
    return __builtin_amdgcn_perm(chi, clo, 0x07060302u);
#else
    return (clo >> 16) | (chi & 0xffff0000u);
#endif
}
static __device__ inline f32x16 mfma32(us8 a, us8 b, f32x16 c) {
    return __builtin_amdgcn_mfma_f32_32x32x16_bf16(
        __builtin_bit_cast(bf16x8, a), __builtin_bit_cast(bf16x8, b), c, 0, 0, 0);
}

// ---------- pre-pass: write K and V^T in exact 32x32x16 A-fragment order ----------
__global__ __launch_bounds__(256)
void prep_frag(const float* __restrict__ K, const float* __restrict__ V,
               unsigned short* __restrict__ KF, unsigned short* __restrict__ VF)
{
    const int bx  = (int)blockIdx.x, t = (int)threadIdx.x;
    const int which = bx & 1, khb = (bx >> 1) & 1, kt = (bx >> 2) & 31, kvh = bx >> 7;
    __shared__ __align__(16) float Ls[32][132];

    const float* src = (which ? V : K) + ((size_t)kvh * SEQ + kt * 64 + khb * 32) * HEAD_DIM;
    #pragma unroll
    for (int i = 0; i < 4; ++i) {
        const int idx = t + i * 256;
        const int r = idx >> 5, c4 = idx & 31;
        *(float4*)&Ls[r][c4 * 4] = *(const float4*)(src + (size_t)r * HEAD_DIM + c4 * 4);
    }
    __syncthreads();

    if (!which) {  // K fragments
        #pragma unroll
        for (int i = 0; i < 2; ++i) {
            const int c = t + i * 256;              // 0..511
            const int lane = c & 63, ds = (c >> 6) & 3, mat = (c >> 8) & 1;
            const int H = lane >> 5;
            const int row = lane & 31;
            const int dim = mat * 64 + ds * 16 + H * 8;
            u32x4 pk;
            #pragma unroll
            for (int jj = 0; jj < 4; ++jj)
                pk[jj] = pk2bf(Ls[row][dim + 2*jj], Ls[row][dim + 2*jj + 1]);
            *(us8*)(KF + ((size_t)(kvh * 32 + kt) * 16 + khb * 8 + mat * 4 + ds) * 512 + lane * 8)
                = __builtin_bit_cast(us8, pk);
        }
    } else {       // V^T fragments
        #pragma unroll
        for (int i = 0; i < 2; ++i) {
            const int c = t + i * 256;
            const int lane = c & 63, db = (c >> 6) & 3, ks = (c >> 8) & 1;
            const int H = lane >> 5;
            const int s0 = ks * 16 + H * 8;
            const int d  = db * 32 + (lane & 31);
            u32x4 pk;
            #pragma unroll
            for (int jj = 0; jj < 4; ++jj)
                pk[jj] = pk2bf(Ls[s0 + 2*jj][d], Ls[s0 + 2*jj + 1][d]);
            *(us8*)(VF + ((size_t)(kvh * 32 + kt) * 16 + khb * 8 + ks * 4 + db) * 512 + lane * 8)
                = __builtin_bit_cast(us8, pk);
        }
    }
}

// ---------- main: KVBLK=128 double-bodies, RACE-FREE stage-after-barrier schedule ----------
// R10 failed: stage-before-barrier with only 2 buffers races (writer of bc^1 concurrent
// with body jb-1's readers of bc^1 in the same inter-barrier window). Fix: issue stage
// AFTER the barrier (WAR fenced: bc^1's last reads completed before their waves passed
// this barrier) and drain own prefetch with vmcnt(0) BEFORE the barrier (RAW fenced;
// cheap: loads were issued one full double-body earlier — same slack as R8's counted
// scheme). 17 barriers, 2-tile ILP per body, setprio on MFMA clusters.
// Grid 256 = 1 block/CU, chained pairs = 33 tiles/block, XCD-affine kv-heads.
__global__ __launch_bounds__(512, 2)
void diff_attn_mfma18(const float* __restrict__ Q,
                      const unsigned short* __restrict__ KF,
                      const unsigned short* __restrict__ VF,
                      float* __restrict__ Out)
{
    __shared__ __align__(16) unsigned short KV[2][2][16384]; // 128 KB: buf x tile-half x 32KB
    __shared__ float rsb[2][2][2][32];                       // [qsel][mat][kh]
    float* cbf = (float*)&KV[0][0][0];                       // epilogue-only alias (69632 B)
#define CB(qs, m, qq, ii) cbf[((((qs) * 2 + (m)) * 32 + (qq)) * 136) + (ii)]

    const int t    = (int)threadIdx.x;
    const int wv   = t >> 6;
    const int ln   = t & 63;
    const int qsel = wv >> 2;       // 0: q-tile A (rows +0..31), 1: q-tile B (rows +32..63)
    const int mat  = (wv >> 1) & 1; // softmax1 (dims 0..63) vs softmax2 (64..127)
    const int kh   = wv & 1;        // k-half of the 64-k tile
    const int q    = ln & 31;
    const int H    = ln >> 5;

    // grid 256 = 1 block/CU; xcd = bx&7 (HW round-robin); kv-head group per XCD pair
    const int bx  = (int)blockIdx.x;
    const int xcd = bx & 7;
    const int u   = bx >> 3;                       // 0..31
    const int kvh = xcd >> 1;
    const int h   = kvh * 4 + (u & 3);
    const int ss  = (u >> 2) | ((xcd & 1) << 3);   // chain slot 0..15

    // stage source: wave wv stages chunks wv*4..wv*4+3 (0..15 = K, 16..31 = V)
    const unsigned short* sgb = (wv < 4 ? KF : VF)
        + ((size_t)kvh * 32 * 16 + (wv & 3) * 4) * 512 + ln * 8;
    auto stage = [&](int jt, int b, int hf) {
        const unsigned short* tb = sgb + (size_t)jt * KT_STRIDE;
        #pragma unroll
        for (int i = 0; i < 4; ++i) {
            __builtin_amdgcn_global_load_lds(
                (const __attribute__((address_space(1))) unsigned int*)(tb + i * 512),
                (__attribute__((address_space(3))) unsigned int*)&KV[b][hf][(wv * 4 + i) * 512],
                16, 0, 0);
        }
    };

    const int kbase = (kh * 8 + mat * 4) * 512;   // K chunks for this wave's role
    const int vbase = (16 + kh * 8) * 512;        // V chunks

    const float qscale = 0.125f * 1.44269504088896340736f;  // 1/8 * log2(e)

    us8 qhi[4];
    auto loadQ = [&](int q0c) {
        const float* qr = Q + ((size_t)h * SEQ + q0c + q) * HEAD_DIM + mat * 64;
        #pragma unroll
        for (int ds = 0; ds < 4; ++ds) {
            const int d0 = ds * 16 + H * 8;
            float x[8];
            *(float4*)&x[0] = *(const float4*)(qr + d0);
            *(float4*)&x[4] = *(const float4*)(qr + d0 + 4);
            us8 hi8;
            #pragma unroll
            for (int j = 0; j < 8; ++j) hi8[j] = f2bf(x[j] * qscale);
            qhi[ds] = hi8;
        }
    };

    f32x16 o[4];                   // O^T: dim = db*32+(r&3)+8*(r>>2)+4H, q-col = q
    f32x4  rsv;

    // exp2(sv+sw rows [rbase,rbase+8)) + mask, pack bf16, accumulate rsv, swap to B-frag
    auto make_bp = [&](const f32x16& sv, const f32x16& sw, int rbase, int kg0, int qg,
                       bool dmask) -> us8 {
        unsigned c0[8];
        if (dmask) {
            #pragma unroll
            for (int r = 0; r < 8; ++r) {
                const int ri = rbase + r;
                const int kg = kg0 + (ri & 3) + ((ri >> 2) << 3);
                float e = (kg <= qg) ? fast_exp2(sv[ri] + sw[ri]) : 0.f;
                c0[r] = __builtin_bit_cast(unsigned, e);
            }
        } else {
            #pragma unroll
            for (int r = 0; r < 8; ++r) {
                const int ri = rbase + r;
                c0[r] = __builtin_bit_cast(unsigned, fast_exp2(sv[ri] + sw[ri]));
            }
        }
        const unsigned pA = pack_hi(c0[0], c0[1]);
        const unsigned pB = pack_hi(c0[2], c0[3]);
        const unsigned pC = pack_hi(c0[4], c0[5]);
        const unsigned pD = pack_hi(c0[6], c0[7]);
        rsv[0] += __builtin_bit_cast(float, pA << 16);
        rsv[1] += __builtin_bit_cast(float, pA & 0xffff0000u);
        rsv[2] += __builtin_bit_cast(float, pB << 16);
        rsv[3] += __builtin_bit_cast(float, pB & 0xffff0000u);
        rsv[0] += __builtin_bit_cast(float, pC << 16);
        rsv[1] += __builtin_bit_cast(float, pC & 0xffff0000u);
        rsv[2] += __builtin_bit_cast(float, pD << 16);
        rsv[3] += __builtin_bit_cast(float, pD & 0xffff0000u);
        u32x4 bw;
#if __has_builtin(__builtin_amdgcn_permlane32_swap)
        {
            u32x2 r02 = __builtin_amdgcn_permlane32_swap(pA, pC, false, false);
            u32x2 r13 = __builtin_amdgcn_permlane32_swap(pB, pD, false, false);
            bw[0] = r02[0]; bw[1] = r13[0]; bw[2] = r02[1]; bw[3] = r13[1];
        }
#else
        {
            const unsigned x1 = H ? pA : pC;
            const unsigned x2 = H ? pB : pD;
            const unsigned t1 = (unsigned)__shfl_xor((int)x1, 32, 64);
            const unsigned t2 = (unsigned)__shfl_xor((int)x2, 32, 64);
            bw[0] = H ? t1 : pA;
            bw[1] = H ? t2 : pB;
            bw[2] = H ? pC : t1;
            bw[3] = H ? pD : t2;
        }
#endif
        return __builtin_bit_cast(us8, bw);
    };

    auto epilogue = [&](int q0c) {
        __syncthreads();   // all compute done; KV free -> cb alias safe
        {
            float rsc = (rsv[0] + rsv[1]) + (rsv[2] + rsv[3]);
            rsc += __shfl_xor(rsc, 32, 64);
            if (ln < 32) rsb[qsel][mat][kh][ln] = rsc;
        }
        if (kh == 1) {
            #pragma unroll
            for (int db = 0; db < 4; ++db)
                #pragma unroll
                for (int i = 0; i < 4; ++i) {
                    float4 v = { o[db][i*4+0], o[db][i*4+1], o[db][i*4+2], o[db][i*4+3] };
                    *(float4*)&CB(qsel, mat, q, db * 32 + 8 * i + 4 * H) = v;
                }
        }
        __syncthreads();
        if (kh == 0) {
            const float l = rsb[qsel][mat][0][q] + rsb[qsel][mat][1][q];
            const float a = mat ? (0.16f / l) : (0.2f / l);
            #pragma unroll
            for (int db = 0; db < 4; ++db)
                #pragma unroll
                for (int i = 0; i < 4; ++i) {
                    float4 v = *(float4*)&CB(qsel, mat, q, db * 32 + 8 * i + 4 * H);
                    o[db][i*4+0] = (o[db][i*4+0] + v.x) * a;
                    o[db][i*4+1] = (o[db][i*4+1] + v.y) * a;
                    o[db][i*4+2] = (o[db][i*4+2] + v.z) * a;
                    o[db][i*4+3] = (o[db][i*4+3] + v.w) * a;
                }
            if (mat == 1) {
                #pragma unroll
                for (int db = 0; db < 4; ++db)
                    #pragma unroll
                    for (int i = 0; i < 4; ++i) {
                        float4 v = { o[db][i*4+0], o[db][i*4+1], o[db][i*4+2], o[db][i*4+3] };
                        *(float4*)&CB(qsel, 1, q, db * 32 + 8 * i + 4 * H) = v;
                    }
            }
        }
        __syncthreads();
        if (mat == 0 && kh == 0) {
            float* ob = Out + ((size_t)h * SEQ + q0c + q) * HEAD_DIM;
            #pragma unroll
            for (int db = 0; db < 4; ++db)
                #pragma unroll
                for (int i = 0; i < 4; ++i) {
                    float4 v = *(float4*)&CB(qsel, 1, q, db * 32 + 8 * i + 4 * H);
                    float4 r;
                    r.x = o[db][i*4+0] - v.x;
                    r.y = o[db][i*4+1] - v.y;
                    r.z = o[db][i*4+2] - v.z;
                    r.w = o[db][i*4+3] - v.w;
                    *(float4*)(ob + db * 32 + 8 * i + 4 * H) = r;
                }
        }
    };

    // pair p: q-rows [64p, 64p+64), k-tiles 0..p, TWO per barrier body.
    // Schedule per body: vmcnt(0) [drain own body-old prefetch] -> barrier ->
    // stage(next body -> other buf) -> ds_read current buf -> compute 2 tiles.
    auto run_pair = [&](int p) {
        const int nseg  = p + 1;
        const int nbody = (nseg + 1) >> 1;
        const int q0    = p * 64 + qsel * 32;
        loadQ(q0);
        #pragma unroll
        for (int i = 0; i < 4; ++i) o[i] = (f32x16)0.f;
        rsv = (f32x4)0.f;

        __syncthreads();                 // prior epilogue's cb reads done -> KV reusable
        stage(0, 0, 0);                  // prologue prefetch (drained at first body's vmcnt)
        if (nseg > 1) stage(1, 0, 1);

        int bc = 0;
        const int qg = q0 + q;
        for (int jb = 0; jb < nbody; ++jb) {
            const int t0 = 2 * jb, t1 = t0 + 1;
            const bool has1 = (t1 < nseg);

            // RAW: own stages for THIS body were issued one double-body ago -> cheap drain
            asm volatile("s_waitcnt vmcnt(0)" ::: "memory");
            __builtin_amdgcn_sched_barrier(0);
            __builtin_amdgcn_s_barrier();    // all waves' stages for this body visible
            __builtin_amdgcn_sched_barrier(0);

            // WAR-safe: bc^1's last readers (body jb-1) completed before passing the
            // barrier above; stage writes are issued only after it.
            if (t0 + 2 < nseg) stage(t0 + 2, bc ^ 1, 0);
            if (t1 + 2 < nseg) stage(t1 + 2, bc ^ 1, 1);

            const unsigned short* b0 = &KV[bc][0][0];
            const unsigned short* b1 = &KV[bc][1][0];

            // both tiles' fragments + QK chains issued up-front (independent reg sets):
            // scheduler interleaves tile1's ds_read/MFMA under tile0's softmax VALU.
            us8 kaf0[4], va0[8];
            #pragma unroll
            for (int ds = 0; ds < 4; ++ds)
                kaf0[ds] = *(const us8*)&b0[kbase + ds * 512 + ln * 8];
            #pragma unroll
            for (int c = 0; c < 8; ++c)
                va0[c] = *(const us8*)&b0[vbase + c * 512 + ln * 8];
            us8 kaf1[4], va1[8];
            if (has1) {
                #pragma unroll
                for (int ds = 0; ds < 4; ++ds)
                    kaf1[ds] = *(const us8*)&b1[kbase + ds * 512 + ln * 8];
                #pragma unroll
                for (int c = 0; c < 8; ++c)
                    va1[c] = *(const us8*)&b1[vbase + c * 512 + ln * 8];
            }

            f32x16 sA = (f32x16)0.f, sB = (f32x16)0.f;
            f32x16 sC = (f32x16)0.f, sD = (f32x16)0.f;
            __builtin_amdgcn_s_setprio(1);
            sA = mfma32(kaf0[0], qhi[0], sA);
            sB = mfma32(kaf0[2], qhi[2], sB);
            sA = mfma32(kaf0[1], qhi[1], sA);
            sB = mfma32(kaf0[3], qhi[3], sB);
            if (has1) {
                sC = mfma32(kaf1[0], qhi[0], sC);
                sD = mfma32(kaf1[2], qhi[2], sD);
                sC = mfma32(kaf1[1], qhi[1], sC);
                sD = mfma32(kaf1[3], qhi[3], sD);
            }
            __builtin_amdgcn_s_setprio(0);

            // tile 0: softmax + PV
            {
                const bool l0  = (t0 == nseg - 1);
                const int  kg0 = t0 * 64 + kh * 32 + 4 * H;
                us8 bp = make_bp(sA, sB, 0, kg0, qg, l0);
                __builtin_amdgcn_s_setprio(1);
                #pragma unroll
                for (int db = 0; db < 4; ++db) o[db] = mfma32(va0[db], bp, o[db]);
                __builtin_amdgcn_s_setprio(0);
                bp = make_bp(sA, sB, 8, kg0, qg, l0);
                __builtin_amdgcn_s_setprio(1);
                #pragma unroll
                for (int db = 0; db < 4; ++db) o[db] = mfma32(va0[4 + db], bp, o[db]);
                __builtin_amdgcn_s_setprio(0);
            }
            // tile 1: softmax + PV
            if (has1) {
                const bool l1  = (t1 == nseg - 1);
                const int  kg1 = t1 * 64 + kh * 32 + 4 * H;
                us8 bp = make_bp(sC, sD, 0, kg1, qg, l1);
                __builtin_amdgcn_s_setprio(1);
                #pragma unroll
                for (int db = 0; db < 4; ++db) o[db] = mfma32(va1[db], bp, o[db]);
                __builtin_amdgcn_s_setprio(0);
                bp = make_bp(sC, sD, 8, kg1, qg, l1);
                __builtin_amdgcn_s_setprio(1);
                #pragma unroll
                for (int db = 0; db < 4; ++db) o[db] = mfma32(va1[4 + db], bp, o[db]);
                __builtin_amdgcn_s_setprio(0);
            }

            bc ^= 1;
        }
        epilogue(q0);
    };

    run_pair(31 - ss);   // heavy pair (32-ss tiles)
    run_pair(ss);        // light pair (ss+1 tiles); 33 tiles total every block
#undef CB
}

extern "C" void kernel_launch(void* const* d_in, const int* in_sizes, int n_in,
                              void* d_out, int out_size, void* d_ws, size_t ws_size,
                              hipStream_t stream) {
    const float* Q = (const float*)d_in[0];
    const float* K = (const float*)d_in[1];
    const float* V = (const float*)d_in[2];
    float* Out = (float*)d_out;

    unsigned short* KF = (unsigned short*)d_ws;             // 2 MB
    unsigned short* VF = KF + (size_t)4 * SEQ * HEAD_DIM;   // 2 MB

    prep_frag<<<512, 256, 0, stream>>>(K, V, KF, VF);
    diff_attn_mfma18<<<256, 512, 0, stream>>>(Q, KF, VF, Out);
}